// Round 7
// baseline (128.268 us; speedup 1.0000x reference)
//
#include <hip/hip_runtime.h>
#include <hip/hip_bf16.h>

// BatchTripletLoss on MI355X — round 7: faithful m201 phase template.
// 256^2 triangular blocks (bn>=bm), BK=64, 8 waves (2M x 4N), 16x16x32 MFMA,
// 2 dbuf x 4 slots {A0,A1,B0,B1}. Wave rows straddle slots: lo=A0[wm*64..+63],
// hi=A1[wm*64..+63]. Per KT, 4 phases, each:
//   {ds_reads; stage; s_barrier; lgkmcnt(0); setprio(1); 16 MFMA; setprio(0); s_barrier}
//   PA: read af_lo(8);              MFMA Q(lo,n01)
//   PB: read bf1(4);  stage A0(k+2); MFMA Q(lo,n23)
//   PC: read af_hi(8); stage B0(k+2); MFMA Q(hi,n23)
//   PD: stage A1,B1(k+2); vmcnt(4); read bf0(k+1) from other buf; MFMA Q(hi,n01)
// vmcnt(4) at PD formally fences ALL cross-wave staging (excludes own <=k-PC loads;
// last common barrier before any k+1 consumer read is k+1-PC-post). Both-sides XOR
// swizzle; XCD-chunked triangular grid; row+col max epilogue.

#define NROWS 8192
#define DIM   1024
#define BT    256
#define BK    64
#define NKT   (DIM / BK)            // 16 K-tiles
#define NBT   (NROWS / BT)          // 32 tile-rows
#define NTRI  (NBT * (NBT + 1) / 2) // 528 blocks

constexpr float EPS = 1e-6f;
constexpr float MARGIN = 0.5f;

typedef __attribute__((ext_vector_type(8))) short short8;
typedef __attribute__((ext_vector_type(4))) float f32x4;

__device__ __forceinline__ unsigned short f2bf_rne(float f) {
    unsigned u = __float_as_uint(f);
    u += 0x7fffu + ((u >> 16) & 1u);
    return (unsigned short)(u >> 16);
}

// ---------------- kernel 1: per-row stats + bf16 conversion ----------------
__global__ void prep_kernel(const float* __restrict__ X, const float* __restrict__ P,
                            unsigned short* __restrict__ Xb,
                            float* __restrict__ cj, float* __restrict__ basei,
                            float* __restrict__ posd, int* __restrict__ valid)
{
    const int tid  = threadIdx.x;
    const int w    = tid >> 6;
    const int lane = tid & 63;
    const int row  = blockIdx.x * 4 + w;
    const float* xr = X + (size_t)row * DIM;

    float sq = 0.f, sm = 0.f, pd = 0.f;
    bool eq = true;
    #pragma unroll
    for (int it = 0; it < 4; ++it) {
        const int idx = it * 256 + lane * 4;
        const float4 x = *(const float4*)(xr + idx);
        const float4 p = *(const float4*)(P + idx);
        sq += x.x*x.x + x.y*x.y + x.z*x.z + x.w*x.w;
        sm += x.x + x.y + x.z + x.w;
        const float d0 = x.x - p.x + EPS, d1 = x.y - p.y + EPS;
        const float d2 = x.z - p.z + EPS, d3 = x.w - p.w + EPS;
        pd += d0*d0 + d1*d1 + d2*d2 + d3*d3;
        eq = eq && (x.x == p.x) && (x.y == p.y) && (x.z == p.z) && (x.w == p.w);
        ushort4 b;
        b.x = f2bf_rne(x.x); b.y = f2bf_rne(x.y); b.z = f2bf_rne(x.z); b.w = f2bf_rne(x.w);
        *(ushort4*)(Xb + (size_t)row * DIM + idx) = b;
    }
    #pragma unroll
    for (int off = 32; off >= 1; off >>= 1) {
        sq += __shfl_xor(sq, off);
        sm += __shfl_xor(sm, off);
        pd += __shfl_xor(pd, off);
    }
    const bool alleq = __all(eq);
    if (lane == 0) {
        cj[row]    = sq - 2.f * EPS * sm;
        basei[row] = sq + 2.f * EPS * sm + (float)DIM * EPS * EPS;
        posd[row]  = sqrtf(pd);
        valid[row] = alleq ? 0 : 1;
    }
}

// ---------------- kernel 2: deep-pipelined symmetric GEMM + row/col max ----------------
// LDS slot = 128 rows x 64 K bf16 = 1024 chunks of 16B. Swizzle: logical (r,c) chunk
// at phys p = r*8 + (c ^ (r&7)). gload_lds writes phys-linear, source pre-permuted.
__global__ __launch_bounds__(512, 2) void gemm_max_kernel(
        const unsigned short* __restrict__ Xb,
        const float* __restrict__ cj,
        float* __restrict__ partmax)
{
    // [buf][slot: A0,A1,B0,B1][1024 chunks * 8 ushort]
    __shared__ alignas(16) unsigned short lds[2][4][8192];
    __shared__ float partrow[4][BT];
    __shared__ float partcol[2][BT];

    const int tid  = threadIdx.x;
    const int lane = tid & 63;
    const int wid  = tid >> 6;        // 0..7
    const int wm   = wid >> 2;        // 0..1  (row sub-block within each A slot)
    const int wn   = wid & 3;         // 0..3  (N quarter: 64 cols)
    const int l15  = lane & 15;
    const int lk   = lane >> 4;       // 0..3
    const int cx0  = lk ^ (l15 & 7);          // K-chunk for ks=0
    const int cx1  = (4 + lk) ^ (l15 & 7);    // ks=1
    const int bslot = 2 + (wn >> 1);          // this wave's B slot
    const int cl0   = (wn & 1) * 64;          // col base within B slot

    // XCD-chunked bijective triangular decode (528 = 8 * 66)
    const int t0 = (blockIdx.x & 7) * (NTRI / 8) + (blockIdx.x >> 3);
    int bm = (int)(32.5f - sqrtf(1056.25f - 2.f * (float)t0));
    if (bm < 0) bm = 0;
    if (bm > NBT - 1) bm = NBT - 1;
    while (bm > 0 && (65 * bm - bm * bm) / 2 > t0) --bm;
    while ((65 * (bm + 1) - (bm + 1) * (bm + 1)) / 2 <= t0) ++bm;
    const int bn = bm + (t0 - (65 * bm - bm * bm) / 2);
    const bool diag = (bm == bn);
    const int Mbase = bm * BT, Nbase = bn * BT;

    f32x4 acc[8][4];
    #pragma unroll
    for (int m = 0; m < 8; ++m)
        #pragma unroll
        for (int n = 0; n < 4; ++n)
            acc[m][n] = (f32x4){0.f, 0.f, 0.f, 0.f};

    #define STAGE(BUF, SLOT, GBASE, KT) do {                                                  \
        _Pragma("unroll")                                                                     \
        for (int inst_ = 0; inst_ < 2; ++inst_) {                                             \
            const int q_ = inst_ * 512 + tid;                                                 \
            const int r_ = q_ >> 3;                                                           \
            const int c_ = (q_ & 7) ^ (r_ & 7);                                               \
            const unsigned short* src_ = Xb + (size_t)((GBASE) + r_) * DIM + (KT) * BK + c_ * 8; \
            unsigned short* dst_ = &lds[BUF][SLOT][(inst_ * 512 + wid * 64) * 8];             \
            __builtin_amdgcn_global_load_lds((const __attribute__((address_space(1))) void*)src_, \
                                             (__attribute__((address_space(3))) void*)dst_, 16, 0, 0); \
        }                                                                                     \
    } while (0)

    // prologue: stage KT0 (8 loads) then KT1 (8); vmcnt(8) -> KT0 landed; barrier; read bf0
    STAGE(0, 0, Mbase, 0); STAGE(0, 1, Mbase + 128, 0);
    STAGE(0, 2, Nbase, 0); STAGE(0, 3, Nbase + 128, 0);
    STAGE(1, 0, Mbase, 1); STAGE(1, 1, Mbase + 128, 1);
    STAGE(1, 2, Nbase, 1); STAGE(1, 3, Nbase + 128, 1);
    asm volatile("s_waitcnt vmcnt(8)" ::: "memory");
    __builtin_amdgcn_s_barrier();

    short8 af[8], bf0[4], bf1[4], bf0n[4];
    {
        const unsigned short* B0 = &lds[0][bslot][0];
        #pragma unroll
        for (int nt = 0; nt < 2; ++nt) {
            bf0[nt * 2]     = *(const short8*)(B0 + ((cl0 + nt * 16 + l15) * 8 + cx0) * 8);
            bf0[nt * 2 + 1] = *(const short8*)(B0 + ((cl0 + nt * 16 + l15) * 8 + cx1) * 8);
        }
    }

    for (int kt = 0; kt < NKT; ++kt) {
        const int b = kt & 1;
        const bool st = (kt + 2 < NKT);     // block-uniform
        const int kp = kt + 2;
        const unsigned short* A0 = &lds[b][0][0];
        const unsigned short* A1 = &lds[b][1][0];
        const unsigned short* Bh = &lds[b][bslot][0];
        const unsigned short* Bn = &lds[b ^ 1][bslot][0];

        // ---- PA: read af_lo (slot A0); MFMA Q(lo, n01)
        #pragma unroll
        for (int mt = 0; mt < 4; ++mt) {
            const int row = wm * 64 + mt * 16 + l15;
            af[mt * 2]     = *(const short8*)(A0 + (row * 8 + cx0) * 8);
            af[mt * 2 + 1] = *(const short8*)(A0 + (row * 8 + cx1) * 8);
        }
        __builtin_amdgcn_s_barrier();
        asm volatile("s_waitcnt lgkmcnt(0)" ::: "memory");
        __builtin_amdgcn_s_setprio(1);
        #pragma unroll
        for (int ks = 0; ks < 2; ++ks)
            #pragma unroll
            for (int mt = 0; mt < 4; ++mt)
                #pragma unroll
                for (int nt = 0; nt < 2; ++nt)
                    acc[mt][nt] = __builtin_amdgcn_mfma_f32_16x16x32_bf16(af[mt*2+ks], bf0[nt*2+ks], acc[mt][nt], 0, 0, 0);
        __builtin_amdgcn_s_setprio(0);
        __builtin_amdgcn_s_barrier();

        // ---- PB: read bf1; stage A0(kt+2) [A0 last read @PA]; MFMA Q(lo, n23)
        #pragma unroll
        for (int nt = 0; nt < 2; ++nt) {
            bf1[nt * 2]     = *(const short8*)(Bh + ((cl0 + 32 + nt * 16 + l15) * 8 + cx0) * 8);
            bf1[nt * 2 + 1] = *(const short8*)(Bh + ((cl0 + 32 + nt * 16 + l15) * 8 + cx1) * 8);
        }
        if (st) STAGE(b, 0, Mbase, kp);
        __builtin_amdgcn_s_barrier();
        asm volatile("s_waitcnt lgkmcnt(0)" ::: "memory");
        __builtin_amdgcn_s_setprio(1);
        #pragma unroll
        for (int ks = 0; ks < 2; ++ks)
            #pragma unroll
            for (int mt = 0; mt < 4; ++mt)
                #pragma unroll
                for (int nt = 0; nt < 2; ++nt)
                    acc[mt][2+nt] = __builtin_amdgcn_mfma_f32_16x16x32_bf16(af[mt*2+ks], bf1[nt*2+ks], acc[mt][2+nt], 0, 0, 0);
        __builtin_amdgcn_s_setprio(0);
        __builtin_amdgcn_s_barrier();

        // ---- PC: read af_hi (slot A1); stage B0(kt+2) [B last read @PB]; MFMA Q(hi, n23)
        #pragma unroll
        for (int mt = 0; mt < 4; ++mt) {
            const int row = wm * 64 + mt * 16 + l15;
            af[mt * 2]     = *(const short8*)(A1 + (row * 8 + cx0) * 8);
            af[mt * 2 + 1] = *(const short8*)(A1 + (row * 8 + cx1) * 8);
        }
        if (st) STAGE(b, 2, Nbase, kp);
        __builtin_amdgcn_s_barrier();
        asm volatile("s_waitcnt lgkmcnt(0)" ::: "memory");
        __builtin_amdgcn_s_setprio(1);
        #pragma unroll
        for (int ks = 0; ks < 2; ++ks)
            #pragma unroll
            for (int mt = 0; mt < 4; ++mt)
                #pragma unroll
                for (int nt = 0; nt < 2; ++nt)
                    acc[4+mt][2+nt] = __builtin_amdgcn_mfma_f32_16x16x32_bf16(af[mt*2+ks], bf1[nt*2+ks], acc[4+mt][2+nt], 0, 0, 0);
        __builtin_amdgcn_s_setprio(0);
        __builtin_amdgcn_s_barrier();

        // ---- PD: stage A1,B1(kt+2) [last read @PC]; vmcnt(4); read bf0(kt+1) from other buf;
        //          MFMA Q(hi, n01) — operands in regs
        if (st) { STAGE(b, 1, Mbase + 128, kp); STAGE(b, 3, Nbase + 128, kp); }
        if (kt < NKT - 1) {
            asm volatile("s_waitcnt vmcnt(4)" ::: "memory");
            #pragma unroll
            for (int nt = 0; nt < 2; ++nt) {
                bf0n[nt * 2]     = *(const short8*)(Bn + ((cl0 + nt * 16 + l15) * 8 + cx0) * 8);
                bf0n[nt * 2 + 1] = *(const short8*)(Bn + ((cl0 + nt * 16 + l15) * 8 + cx1) * 8);
            }
        }
        __builtin_amdgcn_s_barrier();
        asm volatile("s_waitcnt lgkmcnt(0)" ::: "memory");
        __builtin_amdgcn_s_setprio(1);
        #pragma unroll
        for (int ks = 0; ks < 2; ++ks)
            #pragma unroll
            for (int mt = 0; mt < 4; ++mt)
                #pragma unroll
                for (int nt = 0; nt < 2; ++nt)
                    acc[4+mt][nt] = __builtin_amdgcn_mfma_f32_16x16x32_bf16(af[mt*2+ks], bf0[nt*2+ks], acc[4+mt][nt], 0, 0, 0);
        __builtin_amdgcn_s_setprio(0);
        __builtin_amdgcn_s_barrier();

        #pragma unroll
        for (int i = 0; i < 4; ++i) bf0[i] = bf0n[i];
    }
    #undef STAGE

    // ---- epilogue. C/D layout: col = l15, row = lk*4 + reg.
    // Wave rows: m<4 -> wm*64 + m*16 (A0-range), m>=4 -> 128 + wm*64 + (m-4)*16 (A1-range).
    float cv[4];
    #pragma unroll
    for (int n = 0; n < 4; ++n)
        cv[n] = cj[Nbase + wn * 64 + n * 16 + l15];

    // (a) row-max over this wave's 64 cols, combine across wn via LDS
    #pragma unroll
    for (int m = 0; m < 8; ++m) {
        const int rbase = (m < 4) ? (wm * 64 + m * 16) : (128 + wm * 64 + (m - 4) * 16);
        #pragma unroll
        for (int r = 0; r < 4; ++r) {
            const int lrow = rbase + lk * 4 + r;
            float v = -__builtin_inff();
            #pragma unroll
            for (int n = 0; n < 4; ++n) {
                float val = cv[n] - 2.f * acc[m][n][r];
                if (diag && lrow == wn * 64 + n * 16 + l15) val = -__builtin_inff();
                v = fmaxf(v, val);
            }
            #pragma unroll
            for (int off = 8; off >= 1; off >>= 1)
                v = fmaxf(v, __shfl_xor(v, off));
            if (l15 == 0) partrow[wn][lrow] = v;
        }
    }

    // (b) transposed col-max over this wave's 128 rows, combine across wm
    if (!diag) {
        float vt[4];
        #pragma unroll
        for (int n = 0; n < 4; ++n) vt[n] = -__builtin_inff();
        #pragma unroll
        for (int m = 0; m < 8; ++m) {
            const int rbase = (m < 4) ? (wm * 64 + m * 16) : (128 + wm * 64 + (m - 4) * 16);
            #pragma unroll
            for (int r = 0; r < 4; ++r) {
                const float ci = cj[Mbase + rbase + lk * 4 + r];
                #pragma unroll
                for (int n = 0; n < 4; ++n)
                    vt[n] = fmaxf(vt[n], ci - 2.f * acc[m][n][r]);
            }
        }
        #pragma unroll
        for (int n = 0; n < 4; ++n) {
            vt[n] = fmaxf(vt[n], __shfl_xor(vt[n], 16));
            vt[n] = fmaxf(vt[n], __shfl_xor(vt[n], 32));
            if (lk == 0) partcol[wm][wn * 64 + n * 16 + l15] = vt[n];
        }
    }
    __syncthreads();

    if (tid < BT) {
        const float v = fmaxf(fmaxf(partrow[0][tid], partrow[1][tid]),
                              fmaxf(partrow[2][tid], partrow[3][tid]));
        partmax[(size_t)bn * NROWS + Mbase + tid] = v;
    } else if (!diag) {
        const int c = tid - BT;
        partmax[(size_t)bm * NROWS + Nbase + c] = fmaxf(partcol[0][c], partcol[1][c]);
    }
}

// ---------------- kernel 3: per-row finalize + block partial sums ----------------
__global__ void finalize1_kernel(const float* __restrict__ partmax,
                                 const float* __restrict__ basei,
                                 const float* __restrict__ posd,
                                 const int* __restrict__ valid,
                                 float* __restrict__ partials)
{
    const int tid = threadIdx.x;
    const int row = blockIdx.x * 256 + tid;
    float m = -__builtin_inff();
    #pragma unroll 8
    for (int p = 0; p < NBT; ++p)
        m = fmaxf(m, partmax[(size_t)p * NROWS + row]);
    const float d2 = m + basei[row];
    const float mn = sqrtf(fmaxf(d2, 0.f));
    float loss = fmaxf(posd[row] - mn + MARGIN, 0.f);
    float cnt = 1.f;
    if (!valid[row]) { loss = 0.f; cnt = 0.f; }
    #pragma unroll
    for (int off = 32; off >= 1; off >>= 1) {
        loss += __shfl_xor(loss, off);
        cnt  += __shfl_xor(cnt, off);
    }
    __shared__ float sl[4], sc[4];
    const int w = tid >> 6, lane = tid & 63;
    if (lane == 0) { sl[w] = loss; sc[w] = cnt; }
    __syncthreads();
    if (tid == 0) {
        partials[blockIdx.x * 2]     = sl[0] + sl[1] + sl[2] + sl[3];
        partials[blockIdx.x * 2 + 1] = sc[0] + sc[1] + sc[2] + sc[3];
    }
}

// ---------------- kernel 4: final scalar ----------------
__global__ void finalize2_kernel(const float* __restrict__ partials, float* __restrict__ out)
{
    const int tid = threadIdx.x;   // 64 threads
    float l = 0.f, c = 0.f;
    if (tid < 32) { l = partials[tid * 2]; c = partials[tid * 2 + 1]; }
    #pragma unroll
    for (int off = 32; off >= 1; off >>= 1) {
        l += __shfl_xor(l, off);
        c += __shfl_xor(c, off);
    }
    if (tid == 0) out[0] = l / c;
}

extern "C" void kernel_launch(void* const* d_in, const int* in_sizes, int n_in,
                              void* d_out, int out_size, void* d_ws, size_t ws_size,
                              hipStream_t stream)
{
    const float* X = (const float*)d_in[0];   // [8192,1024] f32
    const float* P = (const float*)d_in[1];   // [1024] f32
    float* out = (float*)d_out;
    char* ws = (char*)d_ws;

    unsigned short* Xb = (unsigned short*)ws;                                // 16 MB bf16
    size_t off = (size_t)NROWS * DIM * sizeof(unsigned short);
    float* cj    = (float*)(ws + off);  off += (size_t)NROWS * 4;
    float* basei = (float*)(ws + off);  off += (size_t)NROWS * 4;
    float* posd  = (float*)(ws + off);  off += (size_t)NROWS * 4;
    int*   valid = (int*)(ws + off);    off += (size_t)NROWS * 4;
    float* partmax = (float*)(ws + off); off += (size_t)NBT * NROWS * 4;     // 1 MB
    float* partials = (float*)(ws + off);

    prep_kernel<<<NROWS / 4, 256, 0, stream>>>(X, P, Xb, cj, basei, posd, valid);
    gemm_max_kernel<<<NTRI, 512, 0, stream>>>(Xb, cj, partmax);
    finalize1_kernel<<<NROWS / 256, 256, 0, stream>>>(partmax, basei, posd, valid, partials);
    finalize2_kernel<<<1, 64, 0, stream>>>(partials, out);
}